// Round 5
// baseline (428.705 us; speedup 1.0000x reference)
//
#include <hip/hip_runtime.h>
#include <hip/hip_bf16.h>

#define BATCH 32
#define CDIM  256
#define TDIM  4096

using short8  = __attribute__((ext_vector_type(8))) short;
using floatx4 = __attribute__((ext_vector_type(4))) float;
typedef unsigned short u16;

// RNE float -> bf16 (finite inputs)
__device__ __forceinline__ unsigned f2bf(float f) {
  unsigned u = __float_as_uint(f);
  return (u + 0x7fffu + ((u >> 16) & 1u)) >> 16;
}
__device__ __forceinline__ unsigned cvt_pk_bf16(float a, float b) {
  return f2bf(a) | (f2bf(b) << 16);
}
__device__ __forceinline__ float bf_lo(unsigned u) { return __uint_as_float(u << 16); }
__device__ __forceinline__ float bf_hi(unsigned u) { return __uint_as_float(u & 0xffff0000u); }

// async global->LDS, 16B per lane; LDS dest is wave-uniform base + lane*16.
__device__ __forceinline__ void glds16(const void* g, void* l) {
  __builtin_amdgcn_global_load_lds(
      (const __attribute__((address_space(1))) void*)g,
      (__attribute__((address_space(3))) void*)l, 16, 0, 0);
}

// ---------------------------------------------------------------------------
// Kernel 0a: fused split + transpose.
//   hx = bf16(x), lx = bf16(x-hx), hxT[b][t][j] = hx[b][j][t].
// 128(j) x 128(t) tiles, grid 32*2*32 = 2048, 256 thr.
// All global reads/writes are 128-256 B per-thread contiguous rows.
// LDS: 32 KB, 16B-granule XOR swizzle (g ^= j&15) -> vector row writes,
// ~conflict-free scalar column reads.
// ---------------------------------------------------------------------------
__global__ __launch_bounds__(256)
void split_t2_kernel(const float* __restrict__ x, u16* __restrict__ hx,
                     u16* __restrict__ lx, u16* __restrict__ hxT) {
  __shared__ u16 hs[128 * 128];   // 32 KB

  const int bx  = blockIdx.x;
  const int b   = bx >> 6;
  const int j0  = ((bx >> 5) & 1) << 7;
  const int t0  = (bx & 31) << 7;
  const int tid = threadIdx.x;
  const int jr   = tid >> 1;        // local j row 0..127
  const int half = tid & 1;         // which 64-t half
  const int tl0  = half << 6;

  const size_t xoff = ((size_t)b << 20) + (size_t)(j0 + jr) * TDIM + t0 + tl0;

  float4 a[16];
#pragma unroll
  for (int u = 0; u < 16; ++u) a[u] = ((const float4*)(x + xoff))[u];

  unsigned h[32], l[32];
#pragma unroll
  for (int u = 0; u < 16; ++u) {
    h[2 * u]     = cvt_pk_bf16(a[u].x, a[u].y);
    h[2 * u + 1] = cvt_pk_bf16(a[u].z, a[u].w);
    l[2 * u]     = cvt_pk_bf16(a[u].x - bf_lo(h[2 * u]),     a[u].y - bf_hi(h[2 * u]));
    l[2 * u + 1] = cvt_pk_bf16(a[u].z - bf_lo(h[2 * u + 1]), a[u].w - bf_hi(h[2 * u + 1]));
  }

  u16* ph = hx + xoff;
  u16* pl = lx + xoff;
#pragma unroll
  for (int u = 0; u < 8; ++u) {
    ((uint4*)ph)[u] = make_uint4(h[4 * u], h[4 * u + 1], h[4 * u + 2], h[4 * u + 3]);
    ((uint4*)pl)[u] = make_uint4(l[4 * u], l[4 * u + 1], l[4 * u + 2], l[4 * u + 3]);
  }

  // LDS store h, swizzled: element (jr, tl) at jr*128 + ((tl>>3 ^ (jr&15))<<3) + (tl&7)
#pragma unroll
  for (int g = 0; g < 8; ++g) {
    const int gg = tl0 / 8 + g;                 // global granule 0..15
    const int gs = gg ^ (jr & 15);
    *(uint4*)&hs[jr * 128 + (gs << 3)] =
        make_uint4(h[4 * g], h[4 * g + 1], h[4 * g + 2], h[4 * g + 3]);
  }
  __syncthreads();

  // read column t = tr, pack 64 j, write hxT row (128 B contiguous)
  const int tr = tid >> 1;          // local t 0..127
  const int jh = half << 6;         // j half 0/64
  const int gt = tr >> 3;
  const int t7 = tr & 7;
  unsigned o[32];
#pragma unroll
  for (int p = 0; p < 32; ++p) {
    const int j1 = jh + 2 * p;
    const int j2 = j1 + 1;
    const unsigned lo = hs[j1 * 128 + ((gt ^ (j1 & 15)) << 3) + t7];
    const unsigned hi = hs[j2 * 128 + ((gt ^ (j2 & 15)) << 3) + t7];
    o[p] = lo | (hi << 16);
  }
  u16* pt = hxT + ((size_t)b << 20) + (size_t)(t0 + tr) * CDIM + j0 + jh;
#pragma unroll
  for (int u = 0; u < 8; ++u)
    ((uint4*)pt)[u] = make_uint4(o[4 * u], o[4 * u + 1], o[4 * u + 2], o[4 * u + 3]);
}

// ---------------------------------------------------------------------------
// Kernel 0b: linear split (mid-tier fallback, no hxT).
// ---------------------------------------------------------------------------
__global__ __launch_bounds__(256)
void split_kernel(const float* __restrict__ x, u16* __restrict__ hx,
                  u16* __restrict__ lx) {
  const unsigned gid0 = blockIdx.x * 256 + threadIdx.x;
#pragma unroll
  for (int it = 0; it < 8; ++it) {
    const size_t g8 = ((size_t)gid0 + (size_t)it * (2048u * 256u)) * 8;
    const float4 a = *(const float4*)(x + g8);
    const float4 c = *(const float4*)(x + g8 + 4);
    unsigned h0 = cvt_pk_bf16(a.x, a.y), h1 = cvt_pk_bf16(a.z, a.w);
    unsigned h2 = cvt_pk_bf16(c.x, c.y), h3 = cvt_pk_bf16(c.z, c.w);
    unsigned l0 = cvt_pk_bf16(a.x - bf_lo(h0), a.y - bf_hi(h0));
    unsigned l1 = cvt_pk_bf16(a.z - bf_lo(h1), a.w - bf_hi(h1));
    unsigned l2 = cvt_pk_bf16(c.x - bf_lo(h2), c.y - bf_hi(h2));
    unsigned l3 = cvt_pk_bf16(c.z - bf_lo(h3), c.w - bf_hi(h3));
    *(uint4*)(hx + g8) = make_uint4(h0, h1, h2, h3);
    *(uint4*)(lx + g8) = make_uint4(l0, l1, l2, l3);
  }
}

// ---------------------------------------------------------------------------
// Kernel 1: Gram bf16 GEMM, 64x64 tiles, 2 blocks/CU.
//   S = h h^T + l h^T, E2 = l h^T   (energy[i,j] = S[i,j] + E2[j,i])
// BK = 64, grid 512 (= 2/CU), 256 thr (4 waves 2x2, 32x32/wave).
// Dbuf 2 x 24 KB; per K-step: 6 glds (next) -> vmcnt(6) -> barrier ->
// 12 ds_read_b128 + 16 MFMA -> barrier.  Two co-resident blocks overlap
// each other's barrier drains (the m97 ~3-blocks/CU mechanism).
// ---------------------------------------------------------------------------
__global__ __launch_bounds__(256, 2)
void gram_gemm(const u16* __restrict__ hx, const u16* __restrict__ lx,
               float* __restrict__ S, float* __restrict__ E2) {
  // per buffer: hI 64x64 | lI 64x64 | hJ 64x64 shorts = 12288 shorts (24 KiB)
  __shared__ __align__(16) short lds[2 * 12288];

  const int tid = threadIdx.x;
  const int bx  = blockIdx.x;

  // XCD swizzle: a batch's 16 tile-jobs land on one XCD.
  const int s8  = bx & 7;
  const int seq = bx >> 3;                 // 0..63
  const int b   = s8 + ((seq >> 4) << 3);  // {s8, s8+8, s8+16, s8+24}
  const int job = seq & 15;
  const int i0  = (job >> 2) << 6;         // 0/64/128/192
  const int j0  = (job & 3) << 6;

  const int lane = tid & 63;
  const int w    = tid >> 6;               // 0..3

  // staging: 24 chunks of 1 KiB (8 rows x 128 B); wave w owns c = 4s + w.
  // flat rows: [0,64) hI, [64,128) lI, [128,192) hJ.
  const int rsub = lane >> 3;                    // row within chunk
  const int gsw  = ((lane & 7) ^ rsub) << 3;     // pre-swizzled src granule
  const size_t xb = (size_t)b << 20;
  const u16* src[6];
  int dstoff[6];
#pragma unroll
  for (int s = 0; s < 6; ++s) {
    const int c = (s << 2) + w;
    const u16* base;
    int row;
    if (c < 8)       { base = hx; row = i0 + (c << 3) + rsub; }
    else if (c < 16) { base = lx; row = i0 + ((c - 8) << 3) + rsub; }
    else             { base = hx; row = j0 + ((c - 16) << 3) + rsub; }
    src[s]    = base + xb + (size_t)row * TDIM + gsw;
    dstoff[s] = c << 9;                          // chunk * 512 shorts
  }

  floatx4 acc1[2][2], acc2[2][2];
#pragma unroll
  for (int m = 0; m < 2; ++m)
#pragma unroll
    for (int n = 0; n < 2; ++n) {
      acc1[m][n] = {0.f, 0.f, 0.f, 0.f};
      acc2[m][n] = {0.f, 0.f, 0.f, 0.f};
    }

  const int wib = (w >> 1) << 5;   // 0/32
  const int wjb = (w & 1) << 5;    // 0/32
  const int fr  = lane & 15;
  const int q   = lane >> 4;
  const int f7  = fr & 7;

  const int g0 = ((q)     ^ f7) << 3;
  const int g1 = ((q + 4) ^ f7) << 3;
  const int a0 = (wib + fr) << 6;
  const int a1 = a0 + (16 << 6);
  const int b0 = (wjb + fr) << 6;
  const int b1 = b0 + (16 << 6);

  // prologue: stage K-step 0 into buffer 0
#pragma unroll
  for (int s = 0; s < 6; ++s) glds16(src[s], lds + dstoff[s]);

  for (int ks = 0; ks < 64; ++ks) {
    const int bb = (ks & 1) * 12288;
    if (ks < 63) {
      const int nb = ((ks + 1) & 1) * 12288;
#pragma unroll
      for (int s = 0; s < 6; ++s)
        glds16(src[s] + ((ks + 1) << 6), lds + nb + dstoff[s]);
      asm volatile("s_waitcnt vmcnt(6)" ::: "memory");  // cur buf's 6 done
    } else {
      asm volatile("s_waitcnt vmcnt(0)" ::: "memory");
    }
    __builtin_amdgcn_s_barrier();   // all waves' cur-buf staging landed

    {
      short8 Ah0 = *(const short8*)&lds[bb + a0 + g0];
      short8 Ah1 = *(const short8*)&lds[bb + a1 + g0];
      short8 Al0 = *(const short8*)&lds[bb + 4096 + a0 + g0];
      short8 Al1 = *(const short8*)&lds[bb + 4096 + a1 + g0];
      short8 Bh0 = *(const short8*)&lds[bb + 8192 + b0 + g0];
      short8 Bh1 = *(const short8*)&lds[bb + 8192 + b1 + g0];
      acc1[0][0] = __builtin_amdgcn_mfma_f32_16x16x32_bf16(Ah0, Bh0, acc1[0][0], 0, 0, 0);
      acc1[0][1] = __builtin_amdgcn_mfma_f32_16x16x32_bf16(Ah0, Bh1, acc1[0][1], 0, 0, 0);
      acc1[1][0] = __builtin_amdgcn_mfma_f32_16x16x32_bf16(Ah1, Bh0, acc1[1][0], 0, 0, 0);
      acc1[1][1] = __builtin_amdgcn_mfma_f32_16x16x32_bf16(Ah1, Bh1, acc1[1][1], 0, 0, 0);
      acc2[0][0] = __builtin_amdgcn_mfma_f32_16x16x32_bf16(Al0, Bh0, acc2[0][0], 0, 0, 0);
      acc2[0][1] = __builtin_amdgcn_mfma_f32_16x16x32_bf16(Al0, Bh1, acc2[0][1], 0, 0, 0);
      acc2[1][0] = __builtin_amdgcn_mfma_f32_16x16x32_bf16(Al1, Bh0, acc2[1][0], 0, 0, 0);
      acc2[1][1] = __builtin_amdgcn_mfma_f32_16x16x32_bf16(Al1, Bh1, acc2[1][1], 0, 0, 0);
    }
    {
      short8 Ah0 = *(const short8*)&lds[bb + a0 + g1];
      short8 Ah1 = *(const short8*)&lds[bb + a1 + g1];
      short8 Al0 = *(const short8*)&lds[bb + 4096 + a0 + g1];
      short8 Al1 = *(const short8*)&lds[bb + 4096 + a1 + g1];
      short8 Bh0 = *(const short8*)&lds[bb + 8192 + b0 + g1];
      short8 Bh1 = *(const short8*)&lds[bb + 8192 + b1 + g1];
      acc1[0][0] = __builtin_amdgcn_mfma_f32_16x16x32_bf16(Ah0, Bh0, acc1[0][0], 0, 0, 0);
      acc1[0][1] = __builtin_amdgcn_mfma_f32_16x16x32_bf16(Ah0, Bh1, acc1[0][1], 0, 0, 0);
      acc1[1][0] = __builtin_amdgcn_mfma_f32_16x16x32_bf16(Ah1, Bh0, acc1[1][0], 0, 0, 0);
      acc1[1][1] = __builtin_amdgcn_mfma_f32_16x16x32_bf16(Ah1, Bh1, acc1[1][1], 0, 0, 0);
      acc2[0][0] = __builtin_amdgcn_mfma_f32_16x16x32_bf16(Al0, Bh0, acc2[0][0], 0, 0, 0);
      acc2[0][1] = __builtin_amdgcn_mfma_f32_16x16x32_bf16(Al0, Bh1, acc2[0][1], 0, 0, 0);
      acc2[1][0] = __builtin_amdgcn_mfma_f32_16x16x32_bf16(Al1, Bh0, acc2[1][0], 0, 0, 0);
      acc2[1][1] = __builtin_amdgcn_mfma_f32_16x16x32_bf16(Al1, Bh1, acc2[1][1], 0, 0, 0);
    }
    asm volatile("" ::: "memory");  // fence: next iter's glds stay below
    __builtin_amdgcn_s_barrier();   // all waves' reads of cur buf done
  }

  // epilogue: S = acc1 + acc2, E2 = acc2.  C/D: col = lane&15, row = q*4 + r
#pragma unroll
  for (int m = 0; m < 2; ++m)
#pragma unroll
    for (int n = 0; n < 2; ++n) {
      const int gr = i0 + wib + 16 * m + 4 * q;
      const int gc = j0 + wjb + 16 * n + fr;
      size_t base = (((size_t)b * CDIM + gr) << 8) + gc;
#pragma unroll
      for (int r = 0; r < 4; ++r) {
        S[base + ((size_t)r << 8)]  = acc1[m][n][r] + acc2[m][n][r];
        E2[base + ((size_t)r << 8)] = acc2[m][n][r];
      }
    }
}

// ---------------------------------------------------------------------------
// Kernel 1-fallback: fused fp32 gram (bottom tier).
// ---------------------------------------------------------------------------
__global__ __launch_bounds__(512, 1)
void gram_fused(const float* __restrict__ x,
                float* __restrict__ S, float* __restrict__ E2) {
  __shared__ __align__(16) short hI[128 * 64];
  __shared__ __align__(16) short lI[128 * 64];
  __shared__ __align__(16) short hJ[64 * 64];

  const int tid = threadIdx.x;
  const int bx  = blockIdx.x;
  const int s   = bx & 7;
  const int seq = bx >> 3;
  const int b   = s + ((seq >> 3) << 3);
  const int job = seq & 7;
  const int i0  = (job >> 2) << 7;
  const int j0  = (job & 3) << 6;

  const float* xb = x + ((size_t)b << 20);

  const bool isJ   = tid >= 256;
  const int  irow  = tid >> 1;
  const int  ihalf = tid & 1;
  const int  jrow  = (tid & 255) >> 2;
  const int  jq    = tid & 3;

  const float* pS = isJ
      ? xb + (size_t)(j0 + jrow) * TDIM + (jq << 4)
      : xb + (size_t)(i0 + irow) * TDIM + (ihalf << 5);

  floatx4 acc1[2][2], acc2[2][2];
#pragma unroll
  for (int m = 0; m < 2; ++m)
#pragma unroll
    for (int n = 0; n < 2; ++n) {
      acc1[m][n] = {0.f, 0.f, 0.f, 0.f};
      acc2[m][n] = {0.f, 0.f, 0.f, 0.f};
    }

  const int lane = tid & 63;
  const int w    = tid >> 6;
  const int wib  = (w >> 1) << 5;
  const int wjb  = (w & 1) << 5;
  const int fr   = lane & 15;
  const int q    = lane >> 4;
  const int f7   = fr & 7;

  const int g0 = ((q)     ^ f7) << 3;
  const int g1 = ((q + 4) ^ f7) << 3;
  const int a0 = (wib + fr) << 6;
  const int a1 = a0 + (16 << 6);
  const int b0 = (wjb + fr) << 6;
  const int b1 = b0 + (16 << 6);

  float4 r0, r1, r2, r3, r4, r5, r6, r7;
  r0 = ((const float4*)pS)[0]; r1 = ((const float4*)pS)[1];
  r2 = ((const float4*)pS)[2]; r3 = ((const float4*)pS)[3];
  if (!isJ) {
    r4 = ((const float4*)pS)[4]; r5 = ((const float4*)pS)[5];
    r6 = ((const float4*)pS)[6]; r7 = ((const float4*)pS)[7];
  }

  for (int ks = 0; ks < TDIM / 64; ++ks) {
    unsigned h0 = cvt_pk_bf16(r0.x, r0.y), h1 = cvt_pk_bf16(r0.z, r0.w);
    unsigned h2 = cvt_pk_bf16(r1.x, r1.y), h3 = cvt_pk_bf16(r1.z, r1.w);
    unsigned h4 = cvt_pk_bf16(r2.x, r2.y), h5 = cvt_pk_bf16(r2.z, r2.w);
    unsigned h6 = cvt_pk_bf16(r3.x, r3.y), h7 = cvt_pk_bf16(r3.z, r3.w);
    unsigned h8, h9, hA, hB, hC, hD, hE, hF;
    unsigned l0, l1, l2, l3, l4, l5, l6, l7, l8, l9, lA, lB, lC, lD, lE, lF;
    if (!isJ) {
      h8 = cvt_pk_bf16(r4.x, r4.y); h9 = cvt_pk_bf16(r4.z, r4.w);
      hA = cvt_pk_bf16(r5.x, r5.y); hB = cvt_pk_bf16(r5.z, r5.w);
      hC = cvt_pk_bf16(r6.x, r6.y); hD = cvt_pk_bf16(r6.z, r6.w);
      hE = cvt_pk_bf16(r7.x, r7.y); hF = cvt_pk_bf16(r7.z, r7.w);
      l0 = cvt_pk_bf16(r0.x - bf_lo(h0), r0.y - bf_hi(h0));
      l1 = cvt_pk_bf16(r0.z - bf_lo(h1), r0.w - bf_hi(h1));
      l2 = cvt_pk_bf16(r1.x - bf_lo(h2), r1.y - bf_hi(h2));
      l3 = cvt_pk_bf16(r1.z - bf_lo(h3), r1.w - bf_hi(h3));
      l4 = cvt_pk_bf16(r2.x - bf_lo(h4), r2.y - bf_hi(h4));
      l5 = cvt_pk_bf16(r2.z - bf_lo(h5), r2.w - bf_hi(h5));
      l6 = cvt_pk_bf16(r3.x - bf_lo(h6), r3.y - bf_hi(h6));
      l7 = cvt_pk_bf16(r3.z - bf_lo(h7), r3.w - bf_hi(h7));
      l8 = cvt_pk_bf16(r4.x - bf_lo(h8), r4.y - bf_hi(h8));
      l9 = cvt_pk_bf16(r4.z - bf_lo(h9), r4.w - bf_hi(h9));
      lA = cvt_pk_bf16(r5.x - bf_lo(hA), r5.y - bf_hi(hA));
      lB = cvt_pk_bf16(r5.z - bf_lo(hB), r5.w - bf_hi(hB));
      lC = cvt_pk_bf16(r6.x - bf_lo(hC), r6.y - bf_hi(hC));
      lD = cvt_pk_bf16(r6.z - bf_lo(hD), r6.w - bf_hi(hD));
      lE = cvt_pk_bf16(r7.x - bf_lo(hE), r7.y - bf_hi(hE));
      lF = cvt_pk_bf16(r7.z - bf_lo(hF), r7.w - bf_hi(hF));
    }

    __syncthreads();
    if (!isJ) {
      const int rb = irow << 6;
      const int s7 = irow & 7;
      const int gb = ihalf << 2;
      *(uint4*)&hI[rb + (((gb + 0) ^ s7) << 3)] = make_uint4(h0, h1, h2, h3);
      *(uint4*)&hI[rb + (((gb + 1) ^ s7) << 3)] = make_uint4(h4, h5, h6, h7);
      *(uint4*)&hI[rb + (((gb + 2) ^ s7) << 3)] = make_uint4(h8, h9, hA, hB);
      *(uint4*)&hI[rb + (((gb + 3) ^ s7) << 3)] = make_uint4(hC, hD, hE, hF);
      *(uint4*)&lI[rb + (((gb + 0) ^ s7) << 3)] = make_uint4(l0, l1, l2, l3);
      *(uint4*)&lI[rb + (((gb + 1) ^ s7) << 3)] = make_uint4(l4, l5, l6, l7);
      *(uint4*)&lI[rb + (((gb + 2) ^ s7) << 3)] = make_uint4(l8, l9, lA, lB);
      *(uint4*)&lI[rb + (((gb + 3) ^ s7) << 3)] = make_uint4(lC, lD, lE, lF);
    } else {
      const int rb = jrow << 6;
      const int s7 = jrow & 7;
      const int gb = jq << 1;
      *(uint4*)&hJ[rb + (((gb + 0) ^ s7) << 3)] = make_uint4(h0, h1, h2, h3);
      *(uint4*)&hJ[rb + (((gb + 1) ^ s7) << 3)] = make_uint4(h4, h5, h6, h7);
    }
    __syncthreads();

    if (ks < TDIM / 64 - 1) {
      pS += 64;
      r0 = ((const float4*)pS)[0]; r1 = ((const float4*)pS)[1];
      r2 = ((const float4*)pS)[2]; r3 = ((const float4*)pS)[3];
      if (!isJ) {
        r4 = ((const float4*)pS)[4]; r5 = ((const float4*)pS)[5];
        r6 = ((const float4*)pS)[6]; r7 = ((const float4*)pS)[7];
      }
    }

    {
      short8 Ah0 = *(const short8*)&hI[a0 + g0];
      short8 Ah1 = *(const short8*)&hI[a1 + g0];
      short8 Al0 = *(const short8*)&lI[a0 + g0];
      short8 Al1 = *(const short8*)&lI[a1 + g0];
      short8 Bh0 = *(const short8*)&hJ[b0 + g0];
      short8 Bh1 = *(const short8*)&hJ[b1 + g0];
      acc1[0][0] = __builtin_amdgcn_mfma_f32_16x16x32_bf16(Ah0, Bh0, acc1[0][0], 0, 0, 0);
      acc1[0][1] = __builtin_amdgcn_mfma_f32_16x16x32_bf16(Ah0, Bh1, acc1[0][1], 0, 0, 0);
      acc1[1][0] = __builtin_amdgcn_mfma_f32_16x16x32_bf16(Ah1, Bh0, acc1[1][0], 0, 0, 0);
      acc1[1][1] = __builtin_amdgcn_mfma_f32_16x16x32_bf16(Ah1, Bh1, acc1[1][1], 0, 0, 0);
      acc2[0][0] = __builtin_amdgcn_mfma_f32_16x16x32_bf16(Al0, Bh0, acc2[0][0], 0, 0, 0);
      acc2[0][1] = __builtin_amdgcn_mfma_f32_16x16x32_bf16(Al0, Bh1, acc2[0][1], 0, 0, 0);
      acc2[1][0] = __builtin_amdgcn_mfma_f32_16x16x32_bf16(Al1, Bh0, acc2[1][0], 0, 0, 0);
      acc2[1][1] = __builtin_amdgcn_mfma_f32_16x16x32_bf16(Al1, Bh1, acc2[1][1], 0, 0, 0);
    }
    {
      short8 Ah0 = *(const short8*)&hI[a0 + g1];
      short8 Ah1 = *(const short8*)&hI[a1 + g1];
      short8 Al0 = *(const short8*)&lI[a0 + g1];
      short8 Al1 = *(const short8*)&lI[a1 + g1];
      short8 Bh0 = *(const short8*)&hJ[b0 + g1];
      short8 Bh1 = *(const short8*)&hJ[b1 + g1];
      acc1[0][0] = __builtin_amdgcn_mfma_f32_16x16x32_bf16(Ah0, Bh0, acc1[0][0], 0, 0, 0);
      acc1[0][1] = __builtin_amdgcn_mfma_f32_16x16x32_bf16(Ah0, Bh1, acc1[0][1], 0, 0, 0);
      acc1[1][0] = __builtin_amdgcn_mfma_f32_16x16x32_bf16(Ah1, Bh0, acc1[1][0], 0, 0, 0);
      acc1[1][1] = __builtin_amdgcn_mfma_f32_16x16x32_bf16(Ah1, Bh1, acc1[1][1], 0, 0, 0);
      acc2[0][0] = __builtin_amdgcn_mfma_f32_16x16x32_bf16(Al0, Bh0, acc2[0][0], 0, 0, 0);
      acc2[0][1] = __builtin_amdgcn_mfma_f32_16x16x32_bf16(Al0, Bh1, acc2[0][1], 0, 0, 0);
      acc2[1][0] = __builtin_amdgcn_mfma_f32_16x16x32_bf16(Al1, Bh0, acc2[1][0], 0, 0, 0);
      acc2[1][1] = __builtin_amdgcn_mfma_f32_16x16x32_bf16(Al1, Bh1, acc2[1][1], 0, 0, 0);
    }
  }

#pragma unroll
  for (int m = 0; m < 2; ++m)
#pragma unroll
    for (int n = 0; n < 2; ++n) {
      const int gr = i0 + wib + 16 * m + 4 * q;
      const int gc = j0 + wjb + 16 * n + fr;
      size_t base = (((size_t)b * CDIM + gr) << 8) + gc;
#pragma unroll
      for (int r = 0; r < 4; ++r) {
        S[base + ((size_t)r << 8)]  = acc1[m][n][r] + acc2[m][n][r];
        E2[base + ((size_t)r << 8)] = acc2[m][n][r];
      }
    }
}

// ---------------------------------------------------------------------------
// Kernel 2: softmax over rows of energy = S + E2^T, att = softmax(-energy)
// ---------------------------------------------------------------------------
__global__ __launch_bounds__(256)
void softmax_kernel(const float* __restrict__ S, const float* __restrict__ E2,
                    __hip_bfloat16* __restrict__ att) {
  __shared__ float SR[32][264];
  __shared__ float ST[256][33];

  const int tid = threadIdx.x;
  const int b   = blockIdx.x >> 3;
  const int i0  = (blockIdx.x & 7) << 5;
  const size_t base = (size_t)b << 16;

  {
    const int r  = tid >> 3;
    const int c0 = (tid & 7) << 5;
    const float* p1 = S + base + ((size_t)(i0 + r) << 8) + c0;
#pragma unroll
    for (int u = 0; u < 32; u += 4)
      *(float4*)&SR[r][c0 + u] = *(const float4*)(p1 + u);
  }
  {
    const int c  = tid & 31;
    const int j0 = (tid >> 5) << 5;
    const float* p = E2 + base + i0 + c;
#pragma unroll
    for (int jj = 0; jj < 32; ++jj)
      ST[j0 + jj][c] = p[(size_t)(j0 + jj) << 8];
  }
  __syncthreads();

  const int r  = tid >> 3;
  const int t7 = tid & 7;
  float z[32];
  float m = -3.4e38f;
#pragma unroll
  for (int k = 0; k < 32; ++k) {
    const int j = t7 + (k << 3);
    const float e = SR[r][j] + ST[j][r];
    z[k] = -e;
    m = fmaxf(m, z[k]);
  }
  m = fmaxf(m, __shfl_xor(m, 1, 64));
  m = fmaxf(m, __shfl_xor(m, 2, 64));
  m = fmaxf(m, __shfl_xor(m, 4, 64));
  float ssum = 0.f;
#pragma unroll
  for (int k = 0; k < 32; ++k) { z[k] = expf(z[k] - m); ssum += z[k]; }
  ssum += __shfl_xor(ssum, 1, 64);
  ssum += __shfl_xor(ssum, 2, 64);
  ssum += __shfl_xor(ssum, 4, 64);
  const float inv = 1.f / ssum;

  u16* arow = (u16*)att + base + ((size_t)(i0 + r) << 8);
#pragma unroll
  for (int k = 0; k < 32; ++k) {
    const int j = t7 + (k << 3);
    arow[j] = (u16)f2bf(z[k] * inv);
  }
}

// ---------------------------------------------------------------------------
// Kernel 3: out = gamma * (att @ x) + x.  Full K = 256 resident.
// BOTH panels staged via global_load_lds with pre-swizzled source.
// ---------------------------------------------------------------------------
__global__ __launch_bounds__(512, 1)
void pv_kernel(const float* __restrict__ x, const u16* __restrict__ hxT,
               const __hip_bfloat16* __restrict__ att,
               const float* __restrict__ gamma, float* __restrict__ out) {
  __shared__ __align__(16) short As[128 * 256];   // rows i, k=j contig
  __shared__ __align__(16) short Bs[128 * 256];   // rows t, k=j contig

  const int tid = threadIdx.x;
  const int bx  = blockIdx.x;
  const int b   = bx >> 6;
  const int i0  = ((bx >> 5) & 1) << 7;
  const int t0  = (bx & 31) << 7;

  const u16* asrc = (const u16*)att + ((size_t)b << 16) + ((size_t)i0 << 8);
  const u16* bsrc = hxT + ((size_t)b << 20) + ((size_t)t0 << 8);

  const int lane = tid & 63;
  const int w    = tid >> 6;   // 0..7

  const int rh = lane >> 5;          // row parity within chunk
  const int gd = lane & 31;
#pragma unroll
  for (int s = 0; s < 8; ++s) {
    const int c  = (s << 3) + w;
    const int r  = (c << 1) + rh;
    const int gs = gd ^ (r & 7);
    glds16(asrc + ((size_t)r << 8) + (gs << 3), As + (c << 9));
  }
#pragma unroll
  for (int s = 0; s < 8; ++s) {
    const int c  = (s << 3) + w;
    const int r  = (c << 1) + rh;
    const int gs = gd ^ (r & 7);
    glds16(bsrc + ((size_t)r << 8) + (gs << 3), Bs + (c << 9));
  }

  floatx4 acc[4][2];
#pragma unroll
  for (int m = 0; m < 4; ++m)
#pragma unroll
    for (int n = 0; n < 2; ++n) acc[m][n] = {0.f, 0.f, 0.f, 0.f};

  const int wm = (w >> 2) << 6;   // 0 / 64
  const int wn = (w & 3) << 5;    // 0 / 32 / 64 / 96
  const int fr = lane & 15;
  const int q  = lane >> 4;

  __syncthreads();   // drains all glds

#pragma unroll
  for (int ks = 0; ks < 8; ++ks) {
    short8 Af[4], Bf[2];
#pragma unroll
    for (int m = 0; m < 4; ++m) {
      const int r = wm + 16 * m + fr;
      const int g = ((ks << 2) + q) ^ (r & 7);
      Af[m] = *(const short8*)(As + r * 256 + (g << 3));
    }
#pragma unroll
    for (int n = 0; n < 2; ++n) {
      const int r = wn + 16 * n + fr;
      const int g = ((ks << 2) + q) ^ (r & 7);
      Bf[n] = *(const short8*)(Bs + r * 256 + (g << 3));
    }
#pragma unroll
    for (int m = 0; m < 4; ++m)
#pragma unroll
      for (int n = 0; n < 2; ++n)
        acc[m][n] = __builtin_amdgcn_mfma_f32_16x16x32_bf16(Af[m], Bf[n], acc[m][n], 0, 0, 0);
  }

  const float g = gamma[0];
#pragma unroll
  for (int m = 0; m < 4; ++m)
#pragma unroll
    for (int n = 0; n < 2; ++n) {
      const int gr = i0 + wm + 16 * m + 4 * q;
      const int gc = t0 + wn + 16 * n + fr;
      size_t base = ((size_t)b << 20) + (size_t)gr * TDIM + gc;
#pragma unroll
      for (int r = 0; r < 4; ++r) {
        size_t idx = base + (size_t)r * TDIM;
        out[idx] = g * acc[m][n][r] + x[idx];
      }
    }
}

// ---------------------------------------------------------------------------
// Kernel 3-fallback: full-K pv reading x fp32 directly (mid/bottom tiers).
// ---------------------------------------------------------------------------
__global__ __launch_bounds__(256, 1)
void pv_fused(const float* __restrict__ x, const __hip_bfloat16* __restrict__ att,
              const float* __restrict__ gamma, float* __restrict__ out) {
  __shared__ __align__(16) short As[128 * 256];
  __shared__ __align__(16) short Bs[128 * 256];

  const int tid = threadIdx.x;
  const int bx  = blockIdx.x;
  const int b   = bx >> 6;
  const int i0  = ((bx >> 5) & 1) << 7;
  const int t0  = (bx & 31) << 7;

  const float* xb = x + ((size_t)b << 20) + t0;
  const u16* attb = (const u16*)att + ((size_t)b << 16) + ((size_t)i0 << 8);

  {
    uint4 areg[16];
#pragma unroll
    for (int c = 0; c < 16; ++c) {
      const int p = (c << 8) + tid;
      const int r = p >> 5;
      const int g = (p & 31) ^ (r & 7);
      areg[c] = *(const uint4*)(attb + (r << 8) + (g << 3));
    }
#pragma unroll
    for (int c = 0; c < 16; ++c) {
      const int p = (c << 8) + tid;
      *(uint4*)((char*)As + ((size_t)p << 4)) = areg[c];
    }
  }
  {
    const int tQ = tid & 31;
    const int jg = tid >> 5;
#pragma unroll
    for (int j8 = 0; j8 < 4; ++j8) {
      floatx4 v[8];
#pragma unroll
      for (int u = 0; u < 8; ++u) {
        const int j = (jg << 5) + (j8 << 3) + u;
        v[u] = *(const floatx4*)(xb + (size_t)j * TDIM + (tQ << 2));
      }
#pragma unroll
      for (int tt = 0; tt < 4; ++tt) {
        uint4 wv = make_uint4(cvt_pk_bf16(v[0][tt], v[1][tt]),
                              cvt_pk_bf16(v[2][tt], v[3][tt]),
                              cvt_pk_bf16(v[4][tt], v[5][tt]),
                              cvt_pk_bf16(v[6][tt], v[7][tt]));
        const int row = (tQ << 2) + tt;
        const int gx  = ((jg << 2) + j8) ^ (row & 7);
        *(uint4*)((char*)Bs + (size_t)row * 512 + ((size_t)gx << 4)) = wv;
      }
    }
  }

  floatx4 acc[4][4];
#pragma unroll
  for (int m = 0; m < 4; ++m)
#pragma unroll
    for (int n = 0; n < 4; ++n) acc[m][n] = {0.f, 0.f, 0.f, 0.f};

  const int lane = tid & 63;
  const int w    = tid >> 6;
  const int wm   = (w >> 1) << 6;
  const int wn   = (w & 1) << 6;
  const int fr   = lane & 15;
  const int q    = lane >> 4;

  __syncthreads();

#pragma unroll
  for (int ks = 0; ks < 8; ++ks) {
    short8 Af[4], Bf[4];
#pragma unroll
    for (int m = 0; m < 4; ++m) {
      const int r = wm + 16 * m + fr;
      const int g = ((ks << 2) + q) ^ (r & 7);
      Af[m] = *(const short8*)((char*)As + (size_t)r * 512 + ((size_t)g << 4));
    }
#pragma unroll
    for (int n = 0; n < 4; ++n) {
      const int r = wn + 16 * n + fr;
      const int g = ((ks << 2) + q) ^ (r & 7);
      Bf[n] = *(const short8*)((char*)Bs + (size_t)r * 512 + ((size_t)g << 4));
    }
#pragma unroll
    for (int m = 0; m < 4; ++m)
#pragma unroll
      for (int n = 0; n < 4; ++n)
        acc[m][n] = __builtin_amdgcn_mfma_f32_16x16x32_bf16(Af[m], Bf[n], acc[m][n], 0, 0, 0);
  }

  const float g = gamma[0];
#pragma unroll
  for (int m = 0; m < 4; ++m)
#pragma unroll
    for (int n = 0; n < 4; ++n) {
      const int gr = i0 + wm + 16 * m + 4 * q;
      const int gc = t0 + wn + 16 * n + fr;
      size_t base = ((size_t)b << 20) + (size_t)gr * TDIM + gc;
#pragma unroll
      for (int r = 0; r < 4; ++r) {
        size_t idx = base + (size_t)r * TDIM;
        out[idx] = g * acc[m][n][r] + x[idx];
      }
    }
}

// ---------------------------------------------------------------------------
extern "C" void kernel_launch(void* const* d_in, const int* in_sizes, int n_in,
                              void* d_out, int out_size, void* d_ws, size_t ws_size,
                              hipStream_t stream) {
  (void)in_sizes; (void)n_in; (void)out_size;
  const float* x     = (const float*)d_in[0];
  const float* gamma = (const float*)d_in[1];
  float* out = (float*)d_out;

  const size_t MB = 1024 * 1024;
  const size_t EN = (size_t)BATCH * CDIM * CDIM;       // 2,097,152
  const size_t XN = (size_t)BATCH * CDIM * TDIM;       // 33,554,432
  float* S  = (float*)d_ws;                            // 8 MiB
  float* E2 = S + EN;                                  // 8 MiB
  __hip_bfloat16* att = (__hip_bfloat16*)(E2 + EN);    // 4 MiB
  u16* hx  = (u16*)((char*)d_ws + 20 * MB);            // 64 MiB
  u16* lx  = hx + XN;                                  // 64 MiB
  u16* hxT = lx + XN;                                  // 64 MiB
  const size_t need_full = 20 * MB + 3 * XN * sizeof(u16);  // 212 MiB
  const size_t need_mid  = 20 * MB + 2 * XN * sizeof(u16);  // 148 MiB

  if (ws_size >= need_full) {
    split_t2_kernel<<<dim3(2048), dim3(256), 0, stream>>>(x, hx, lx, hxT);
    gram_gemm<<<dim3(512), dim3(256), 0, stream>>>(hx, lx, S, E2);
    softmax_kernel<<<dim3(BATCH * 8), dim3(256), 0, stream>>>(S, E2, att);
    pv_kernel<<<dim3(2048), dim3(512), 0, stream>>>(x, hxT, att, gamma, out);
  } else if (ws_size >= need_mid) {
    split_kernel<<<dim3(2048), dim3(256), 0, stream>>>(x, hx, lx);
    gram_gemm<<<dim3(512), dim3(256), 0, stream>>>(hx, lx, S, E2);
    softmax_kernel<<<dim3(BATCH * 8), dim3(256), 0, stream>>>(S, E2, att);
    pv_fused<<<dim3(2048), dim3(256), 0, stream>>>(x, att, gamma, out);
  } else {
    gram_fused<<<dim3(256), dim3(512), 0, stream>>>(x, S, E2);
    softmax_kernel<<<dim3(BATCH * 8), dim3(256), 0, stream>>>(S, E2, att);
    pv_fused<<<dim3(2048), dim3(256), 0, stream>>>(x, att, gamma, out);
  }
}

// Round 6
// 367.941 us; speedup vs baseline: 1.1651x; 1.1651x over previous
//
#include <hip/hip_runtime.h>
#include <hip/hip_bf16.h>

#define BATCH 32
#define CDIM  256
#define TDIM  4096

using short8  = __attribute__((ext_vector_type(8))) short;
using floatx4 = __attribute__((ext_vector_type(4))) float;
typedef unsigned short u16;

// RNE float -> bf16 (finite inputs)
__device__ __forceinline__ unsigned f2bf(float f) {
  unsigned u = __float_as_uint(f);
  return (u + 0x7fffu + ((u >> 16) & 1u)) >> 16;
}
__device__ __forceinline__ unsigned cvt_pk_bf16(float a, float b) {
  return f2bf(a) | (f2bf(b) << 16);
}
__device__ __forceinline__ float bf_lo(unsigned u) { return __uint_as_float(u << 16); }
__device__ __forceinline__ float bf_hi(unsigned u) { return __uint_as_float(u & 0xffff0000u); }

// async global->LDS, 16B per lane; LDS dest is wave-uniform base + lane*16.
__device__ __forceinline__ void glds16(const void* g, void* l) {
  __builtin_amdgcn_global_load_lds(
      (const __attribute__((address_space(1))) void*)g,
      (__attribute__((address_space(3))) void*)l, 16, 0, 0);
}

// ---------------------------------------------------------------------------
// Kernel 0: linear split prepass.  hx = bf16(x), lx = bf16(x - hx).
// Pure streaming, fully coalesced. 256 MiB traffic -> ~45 us (HBM roofline).
// ---------------------------------------------------------------------------
__global__ __launch_bounds__(256)
void split_kernel(const float* __restrict__ x, u16* __restrict__ hx,
                  u16* __restrict__ lx) {
  const unsigned gid0 = blockIdx.x * 256 + threadIdx.x;
#pragma unroll
  for (int it = 0; it < 8; ++it) {
    const size_t g8 = ((size_t)gid0 + (size_t)it * (2048u * 256u)) * 8;
    const float4 a = *(const float4*)(x + g8);
    const float4 c = *(const float4*)(x + g8 + 4);
    unsigned h0 = cvt_pk_bf16(a.x, a.y), h1 = cvt_pk_bf16(a.z, a.w);
    unsigned h2 = cvt_pk_bf16(c.x, c.y), h3 = cvt_pk_bf16(c.z, c.w);
    unsigned l0 = cvt_pk_bf16(a.x - bf_lo(h0), a.y - bf_hi(h0));
    unsigned l1 = cvt_pk_bf16(a.z - bf_lo(h1), a.w - bf_hi(h1));
    unsigned l2 = cvt_pk_bf16(c.x - bf_lo(h2), c.y - bf_hi(h2));
    unsigned l3 = cvt_pk_bf16(c.z - bf_lo(h3), c.w - bf_hi(h3));
    *(uint4*)(hx + g8) = make_uint4(h0, h1, h2, h3);
    *(uint4*)(lx + g8) = make_uint4(l0, l1, l2, l3);
  }
}

// ---------------------------------------------------------------------------
// Kernel 1: Gram bf16 GEMM, 64x64 tiles, TRIPLE-buffered depth-2 prefetch.
//   S = h h^T + l h^T, E2 = l h^T   (energy[i,j] = S[i,j] + E2[j,i])
// BK = 64, grid 512, 256 thr (4 waves 2x2, 32x32/wave), 2 blocks/CU (72 KB).
// Per K-step ks: issue 6 glds for ks+2 -> vmcnt(12) (waits ks's loads only;
// ks+1 and ks+2 stay in flight ACROSS the barrier) -> barrier -> ds_read +
// 16 MFMA -> barrier.  Prefetch distance = 2 steps (~300-400 cyc) to cover
// the 200-900 cyc global-load latency that the depth-1 version exposed.
// ---------------------------------------------------------------------------
__global__ __launch_bounds__(256, 2)
void gram_gemm(const u16* __restrict__ hx, const u16* __restrict__ lx,
               float* __restrict__ S, float* __restrict__ E2) {
  // per buffer: hI 64x64 | lI 64x64 | hJ 64x64 shorts = 12288 shorts (24 KiB)
  __shared__ __align__(16) short lds[3 * 12288];

  const int tid = threadIdx.x;
  const int bx  = blockIdx.x;

  // XCD swizzle: a batch's 16 tile-jobs land on one XCD.
  const int s8  = bx & 7;
  const int seq = bx >> 3;                 // 0..63
  const int b   = s8 + ((seq >> 4) << 3);  // {s8, s8+8, s8+16, s8+24}
  const int job = seq & 15;
  const int i0  = (job >> 2) << 6;         // 0/64/128/192
  const int j0  = (job & 3) << 6;

  const int lane = tid & 63;
  const int w    = tid >> 6;               // 0..3

  // staging: 24 chunks of 1 KiB (8 rows x 128 B); wave w owns c = 4s + w.
  // flat rows: [0,64) hI, [64,128) lI, [128,192) hJ.
  const int rsub = lane >> 3;                    // row within chunk
  const int gsw  = ((lane & 7) ^ rsub) << 3;     // pre-swizzled src granule
  const size_t xb = (size_t)b << 20;
  const u16* src[6];
  int dstoff[6];
#pragma unroll
  for (int s = 0; s < 6; ++s) {
    const int c = (s << 2) + w;
    const u16* base;
    int row;
    if (c < 8)       { base = hx; row = i0 + (c << 3) + rsub; }
    else if (c < 16) { base = lx; row = i0 + ((c - 8) << 3) + rsub; }
    else             { base = hx; row = j0 + ((c - 16) << 3) + rsub; }
    src[s]    = base + xb + (size_t)row * TDIM + gsw;
    dstoff[s] = c << 9;                          // chunk * 512 shorts
  }

  floatx4 acc1[2][2], acc2[2][2];
#pragma unroll
  for (int m = 0; m < 2; ++m)
#pragma unroll
    for (int n = 0; n < 2; ++n) {
      acc1[m][n] = {0.f, 0.f, 0.f, 0.f};
      acc2[m][n] = {0.f, 0.f, 0.f, 0.f};
    }

  const int wib = (w >> 1) << 5;   // 0/32
  const int wjb = (w & 1) << 5;    // 0/32
  const int fr  = lane & 15;
  const int q   = lane >> 4;
  const int f7  = fr & 7;

  const int g0 = ((q)     ^ f7) << 3;
  const int g1 = ((q + 4) ^ f7) << 3;
  const int a0 = (wib + fr) << 6;
  const int a1 = a0 + (16 << 6);
  const int b0 = (wjb + fr) << 6;
  const int b1 = b0 + (16 << 6);

  // prologue: stage K-steps 0 and 1 into buffers 0 and 1 (12 glds in flight)
#pragma unroll
  for (int s = 0; s < 6; ++s) glds16(src[s], lds + dstoff[s]);
#pragma unroll
  for (int s = 0; s < 6; ++s) glds16(src[s] + 64, lds + 12288 + dstoff[s]);

  int cur = 0;            // LDS offset of buf[ks % 3]
  int nx2 = 2 * 12288;    // LDS offset of buf[(ks+2) % 3]

  for (int ks = 0; ks < 64; ++ks) {
    if (ks < 62) {
#pragma unroll
      for (int s = 0; s < 6; ++s)
        glds16(src[s] + ((ks + 2) << 6), lds + nx2 + dstoff[s]);
      asm volatile("s_waitcnt vmcnt(12)" ::: "memory");  // ks's 6 landed
    } else if (ks == 62) {
      asm volatile("s_waitcnt vmcnt(6)" ::: "memory");
    } else {
      asm volatile("s_waitcnt vmcnt(0)" ::: "memory");
    }
    __builtin_amdgcn_s_barrier();   // all waves' cur-buf staging landed

    {
      short8 Ah0 = *(const short8*)&lds[cur + a0 + g0];
      short8 Ah1 = *(const short8*)&lds[cur + a1 + g0];
      short8 Al0 = *(const short8*)&lds[cur + 4096 + a0 + g0];
      short8 Al1 = *(const short8*)&lds[cur + 4096 + a1 + g0];
      short8 Bh0 = *(const short8*)&lds[cur + 8192 + b0 + g0];
      short8 Bh1 = *(const short8*)&lds[cur + 8192 + b1 + g0];
      acc1[0][0] = __builtin_amdgcn_mfma_f32_16x16x32_bf16(Ah0, Bh0, acc1[0][0], 0, 0, 0);
      acc1[0][1] = __builtin_amdgcn_mfma_f32_16x16x32_bf16(Ah0, Bh1, acc1[0][1], 0, 0, 0);
      acc1[1][0] = __builtin_amdgcn_mfma_f32_16x16x32_bf16(Ah1, Bh0, acc1[1][0], 0, 0, 0);
      acc1[1][1] = __builtin_amdgcn_mfma_f32_16x16x32_bf16(Ah1, Bh1, acc1[1][1], 0, 0, 0);
      acc2[0][0] = __builtin_amdgcn_mfma_f32_16x16x32_bf16(Al0, Bh0, acc2[0][0], 0, 0, 0);
      acc2[0][1] = __builtin_amdgcn_mfma_f32_16x16x32_bf16(Al0, Bh1, acc2[0][1], 0, 0, 0);
      acc2[1][0] = __builtin_amdgcn_mfma_f32_16x16x32_bf16(Al1, Bh0, acc2[1][0], 0, 0, 0);
      acc2[1][1] = __builtin_amdgcn_mfma_f32_16x16x32_bf16(Al1, Bh1, acc2[1][1], 0, 0, 0);
    }
    {
      short8 Ah0 = *(const short8*)&lds[cur + a0 + g1];
      short8 Ah1 = *(const short8*)&lds[cur + a1 + g1];
      short8 Al0 = *(const short8*)&lds[cur + 4096 + a0 + g1];
      short8 Al1 = *(const short8*)&lds[cur + 4096 + a1 + g1];
      short8 Bh0 = *(const short8*)&lds[cur + 8192 + b0 + g1];
      short8 Bh1 = *(const short8*)&lds[cur + 8192 + b1 + g1];
      acc1[0][0] = __builtin_amdgcn_mfma_f32_16x16x32_bf16(Ah0, Bh0, acc1[0][0], 0, 0, 0);
      acc1[0][1] = __builtin_amdgcn_mfma_f32_16x16x32_bf16(Ah0, Bh1, acc1[0][1], 0, 0, 0);
      acc1[1][0] = __builtin_amdgcn_mfma_f32_16x16x32_bf16(Ah1, Bh0, acc1[1][0], 0, 0, 0);
      acc1[1][1] = __builtin_amdgcn_mfma_f32_16x16x32_bf16(Ah1, Bh1, acc1[1][1], 0, 0, 0);
      acc2[0][0] = __builtin_amdgcn_mfma_f32_16x16x32_bf16(Al0, Bh0, acc2[0][0], 0, 0, 0);
      acc2[0][1] = __builtin_amdgcn_mfma_f32_16x16x32_bf16(Al0, Bh1, acc2[0][1], 0, 0, 0);
      acc2[1][0] = __builtin_amdgcn_mfma_f32_16x16x32_bf16(Al1, Bh0, acc2[1][0], 0, 0, 0);
      acc2[1][1] = __builtin_amdgcn_mfma_f32_16x16x32_bf16(Al1, Bh1, acc2[1][1], 0, 0, 0);
    }
    asm volatile("" ::: "memory");  // keep next iter's glds below the barrier
    __builtin_amdgcn_s_barrier();   // all waves' reads of cur buf done

    cur += 12288; if (cur == 36864) cur = 0;
    nx2 += 12288; if (nx2 == 36864) nx2 = 0;
  }

  // epilogue: S = acc1 + acc2, E2 = acc2.  C/D: col = lane&15, row = q*4 + r
#pragma unroll
  for (int m = 0; m < 2; ++m)
#pragma unroll
    for (int n = 0; n < 2; ++n) {
      const int gr = i0 + wib + 16 * m + 4 * q;
      const int gc = j0 + wjb + 16 * n + fr;
      size_t base = (((size_t)b * CDIM + gr) << 8) + gc;
#pragma unroll
      for (int r = 0; r < 4; ++r) {
        S[base + ((size_t)r << 8)]  = acc1[m][n][r] + acc2[m][n][r];
        E2[base + ((size_t)r << 8)] = acc2[m][n][r];
      }
    }
}

// ---------------------------------------------------------------------------
// Kernel 1-fallback: fused fp32 gram (bottom tier only).
// ---------------------------------------------------------------------------
__global__ __launch_bounds__(512, 1)
void gram_fused(const float* __restrict__ x,
                float* __restrict__ S, float* __restrict__ E2) {
  __shared__ __align__(16) short hI[128 * 64];
  __shared__ __align__(16) short lI[128 * 64];
  __shared__ __align__(16) short hJ[64 * 64];

  const int tid = threadIdx.x;
  const int bx  = blockIdx.x;
  const int s   = bx & 7;
  const int seq = bx >> 3;
  const int b   = s + ((seq >> 3) << 3);
  const int job = seq & 7;
  const int i0  = (job >> 2) << 7;
  const int j0  = (job & 3) << 6;

  const float* xb = x + ((size_t)b << 20);

  const bool isJ   = tid >= 256;
  const int  irow  = tid >> 1;
  const int  ihalf = tid & 1;
  const int  jrow  = (tid & 255) >> 2;
  const int  jq    = tid & 3;

  const float* pS = isJ
      ? xb + (size_t)(j0 + jrow) * TDIM + (jq << 4)
      : xb + (size_t)(i0 + irow) * TDIM + (ihalf << 5);

  floatx4 acc1[2][2], acc2[2][2];
#pragma unroll
  for (int m = 0; m < 2; ++m)
#pragma unroll
    for (int n = 0; n < 2; ++n) {
      acc1[m][n] = {0.f, 0.f, 0.f, 0.f};
      acc2[m][n] = {0.f, 0.f, 0.f, 0.f};
    }

  const int lane = tid & 63;
  const int w    = tid >> 6;
  const int wib  = (w >> 1) << 5;
  const int wjb  = (w & 1) << 5;
  const int fr   = lane & 15;
  const int q    = lane >> 4;
  const int f7   = fr & 7;

  const int g0 = ((q)     ^ f7) << 3;
  const int g1 = ((q + 4) ^ f7) << 3;
  const int a0 = (wib + fr) << 6;
  const int a1 = a0 + (16 << 6);
  const int b0 = (wjb + fr) << 6;
  const int b1 = b0 + (16 << 6);

  float4 r0, r1, r2, r3, r4, r5, r6, r7;
  r0 = ((const float4*)pS)[0]; r1 = ((const float4*)pS)[1];
  r2 = ((const float4*)pS)[2]; r3 = ((const float4*)pS)[3];
  if (!isJ) {
    r4 = ((const float4*)pS)[4]; r5 = ((const float4*)pS)[5];
    r6 = ((const float4*)pS)[6]; r7 = ((const float4*)pS)[7];
  }

  for (int ks = 0; ks < TDIM / 64; ++ks) {
    unsigned h0 = cvt_pk_bf16(r0.x, r0.y), h1 = cvt_pk_bf16(r0.z, r0.w);
    unsigned h2 = cvt_pk_bf16(r1.x, r1.y), h3 = cvt_pk_bf16(r1.z, r1.w);
    unsigned h4 = cvt_pk_bf16(r2.x, r2.y), h5 = cvt_pk_bf16(r2.z, r2.w);
    unsigned h6 = cvt_pk_bf16(r3.x, r3.y), h7 = cvt_pk_bf16(r3.z, r3.w);
    unsigned h8, h9, hA, hB, hC, hD, hE, hF;
    unsigned l0, l1, l2, l3, l4, l5, l6, l7, l8, l9, lA, lB, lC, lD, lE, lF;
    if (!isJ) {
      h8 = cvt_pk_bf16(r4.x, r4.y); h9 = cvt_pk_bf16(r4.z, r4.w);
      hA = cvt_pk_bf16(r5.x, r5.y); hB = cvt_pk_bf16(r5.z, r5.w);
      hC = cvt_pk_bf16(r6.x, r6.y); hD = cvt_pk_bf16(r6.z, r6.w);
      hE = cvt_pk_bf16(r7.x, r7.y); hF = cvt_pk_bf16(r7.z, r7.w);
      l0 = cvt_pk_bf16(r0.x - bf_lo(h0), r0.y - bf_hi(h0));
      l1 = cvt_pk_bf16(r0.z - bf_lo(h1), r0.w - bf_hi(h1));
      l2 = cvt_pk_bf16(r1.x - bf_lo(h2), r1.y - bf_hi(h2));
      l3 = cvt_pk_bf16(r1.z - bf_lo(h3), r1.w - bf_hi(h3));
      l4 = cvt_pk_bf16(r2.x - bf_lo(h4), r2.y - bf_hi(h4));
      l5 = cvt_pk_bf16(r2.z - bf_lo(h5), r2.w - bf_hi(h5));
      l6 = cvt_pk_bf16(r3.x - bf_lo(h6), r3.y - bf_hi(h6));
      l7 = cvt_pk_bf16(r3.z - bf_lo(h7), r3.w - bf_hi(h7));
      l8 = cvt_pk_bf16(r4.x - bf_lo(h8), r4.y - bf_hi(h8));
      l9 = cvt_pk_bf16(r4.z - bf_lo(h9), r4.w - bf_hi(h9));
      lA = cvt_pk_bf16(r5.x - bf_lo(hA), r5.y - bf_hi(hA));
      lB = cvt_pk_bf16(r5.z - bf_lo(hB), r5.w - bf_hi(hB));
      lC = cvt_pk_bf16(r6.x - bf_lo(hC), r6.y - bf_hi(hC));
      lD = cvt_pk_bf16(r6.z - bf_lo(hD), r6.w - bf_hi(hD));
      lE = cvt_pk_bf16(r7.x - bf_lo(hE), r7.y - bf_hi(hE));
      lF = cvt_pk_bf16(r7.z - bf_lo(hF), r7.w - bf_hi(hF));
    }

    __syncthreads();
    if (!isJ) {
      const int rb = irow << 6;
      const int s7 = irow & 7;
      const int gb = ihalf << 2;
      *(uint4*)&hI[rb + (((gb + 0) ^ s7) << 3)] = make_uint4(h0, h1, h2, h3);
      *(uint4*)&hI[rb + (((gb + 1) ^ s7) << 3)] = make_uint4(h4, h5, h6, h7);
      *(uint4*)&hI[rb + (((gb + 2) ^ s7) << 3)] = make_uint4(h8, h9, hA, hB);
      *(uint4*)&hI[rb + (((gb + 3) ^ s7) << 3)] = make_uint4(hC, hD, hE, hF);
      *(uint4*)&lI[rb + (((gb + 0) ^ s7) << 3)] = make_uint4(l0, l1, l2, l3);
      *(uint4*)&lI[rb + (((gb + 1) ^ s7) << 3)] = make_uint4(l4, l5, l6, l7);
      *(uint4*)&lI[rb + (((gb + 2) ^ s7) << 3)] = make_uint4(l8, l9, lA, lB);
      *(uint4*)&lI[rb + (((gb + 3) ^ s7) << 3)] = make_uint4(lC, lD, lE, lF);
    } else {
      const int rb = jrow << 6;
      const int s7 = jrow & 7;
      const int gb = jq << 1;
      *(uint4*)&hJ[rb + (((gb + 0) ^ s7) << 3)] = make_uint4(h0, h1, h2, h3);
      *(uint4*)&hJ[rb + (((gb + 1) ^ s7) << 3)] = make_uint4(h4, h5, h6, h7);
    }
    __syncthreads();

    if (ks < TDIM / 64 - 1) {
      pS += 64;
      r0 = ((const float4*)pS)[0]; r1 = ((const float4*)pS)[1];
      r2 = ((const float4*)pS)[2]; r3 = ((const float4*)pS)[3];
      if (!isJ) {
        r4 = ((const float4*)pS)[4]; r5 = ((const float4*)pS)[5];
        r6 = ((const float4*)pS)[6]; r7 = ((const float4*)pS)[7];
      }
    }

    {
      short8 Ah0 = *(const short8*)&hI[a0 + g0];
      short8 Ah1 = *(const short8*)&hI[a1 + g0];
      short8 Al0 = *(const short8*)&lI[a0 + g0];
      short8 Al1 = *(const short8*)&lI[a1 + g0];
      short8 Bh0 = *(const short8*)&hJ[b0 + g0];
      short8 Bh1 = *(const short8*)&hJ[b1 + g0];
      acc1[0][0] = __builtin_amdgcn_mfma_f32_16x16x32_bf16(Ah0, Bh0, acc1[0][0], 0, 0, 0);
      acc1[0][1] = __builtin_amdgcn_mfma_f32_16x16x32_bf16(Ah0, Bh1, acc1[0][1], 0, 0, 0);
      acc1[1][0] = __builtin_amdgcn_mfma_f32_16x16x32_bf16(Ah1, Bh0, acc1[1][0], 0, 0, 0);
      acc1[1][1] = __builtin_amdgcn_mfma_f32_16x16x32_bf16(Ah1, Bh1, acc1[1][1], 0, 0, 0);
      acc2[0][0] = __builtin_amdgcn_mfma_f32_16x16x32_bf16(Al0, Bh0, acc2[0][0], 0, 0, 0);
      acc2[0][1] = __builtin_amdgcn_mfma_f32_16x16x32_bf16(Al0, Bh1, acc2[0][1], 0, 0, 0);
      acc2[1][0] = __builtin_amdgcn_mfma_f32_16x16x32_bf16(Al1, Bh0, acc2[1][0], 0, 0, 0);
      acc2[1][1] = __builtin_amdgcn_mfma_f32_16x16x32_bf16(Al1, Bh1, acc2[1][1], 0, 0, 0);
    }
    {
      short8 Ah0 = *(const short8*)&hI[a0 + g1];
      short8 Ah1 = *(const short8*)&hI[a1 + g1];
      short8 Al0 = *(const short8*)&lI[a0 + g1];
      short8 Al1 = *(const short8*)&lI[a1 + g1];
      short8 Bh0 = *(const short8*)&hJ[b0 + g1];
      short8 Bh1 = *(const short8*)&hJ[b1 + g1];
      acc1[0][0] = __builtin_amdgcn_mfma_f32_16x16x32_bf16(Ah0, Bh0, acc1[0][0], 0, 0, 0);
      acc1[0][1] = __builtin_amdgcn_mfma_f32_16x16x32_bf16(Ah0, Bh1, acc1[0][1], 0, 0, 0);
      acc1[1][0] = __builtin_amdgcn_mfma_f32_16x16x32_bf16(Ah1, Bh0, acc1[1][0], 0, 0, 0);
      acc1[1][1] = __builtin_amdgcn_mfma_f32_16x16x32_bf16(Ah1, Bh1, acc1[1][1], 0, 0, 0);
      acc2[0][0] = __builtin_amdgcn_mfma_f32_16x16x32_bf16(Al0, Bh0, acc2[0][0], 0, 0, 0);
      acc2[0][1] = __builtin_amdgcn_mfma_f32_16x16x32_bf16(Al0, Bh1, acc2[0][1], 0, 0, 0);
      acc2[1][0] = __builtin_amdgcn_mfma_f32_16x16x32_bf16(Al1, Bh0, acc2[1][0], 0, 0, 0);
      acc2[1][1] = __builtin_amdgcn_mfma_f32_16x16x32_bf16(Al1, Bh1, acc2[1][1], 0, 0, 0);
    }
  }

#pragma unroll
  for (int m = 0; m < 2; ++m)
#pragma unroll
    for (int n = 0; n < 2; ++n) {
      const int gr = i0 + wib + 16 * m + 4 * q;
      const int gc = j0 + wjb + 16 * n + fr;
      size_t base = (((size_t)b * CDIM + gr) << 8) + gc;
#pragma unroll
      for (int r = 0; r < 4; ++r) {
        S[base + ((size_t)r << 8)]  = acc1[m][n][r] + acc2[m][n][r];
        E2[base + ((size_t)r << 8)] = acc2[m][n][r];
      }
    }
}

// ---------------------------------------------------------------------------
// Kernel 2: softmax over rows of energy = S + E2^T, att = softmax(-energy)
// ---------------------------------------------------------------------------
__global__ __launch_bounds__(256)
void softmax_kernel(const float* __restrict__ S, const float* __restrict__ E2,
                    __hip_bfloat16* __restrict__ att) {
  __shared__ float SR[32][264];
  __shared__ float ST[256][33];

  const int tid = threadIdx.x;
  const int b   = blockIdx.x >> 3;
  const int i0  = (blockIdx.x & 7) << 5;
  const size_t base = (size_t)b << 16;

  {
    const int r  = tid >> 3;
    const int c0 = (tid & 7) << 5;
    const float* p1 = S + base + ((size_t)(i0 + r) << 8) + c0;
#pragma unroll
    for (int u = 0; u < 32; u += 4)
      *(float4*)&SR[r][c0 + u] = *(const float4*)(p1 + u);
  }
  {
    const int c  = tid & 31;
    const int j0 = (tid >> 5) << 5;
    const float* p = E2 + base + i0 + c;
#pragma unroll
    for (int jj = 0; jj < 32; ++jj)
      ST[j0 + jj][c] = p[(size_t)(j0 + jj) << 8];
  }
  __syncthreads();

  const int r  = tid >> 3;
  const int t7 = tid & 7;
  float z[32];
  float m = -3.4e38f;
#pragma unroll
  for (int k = 0; k < 32; ++k) {
    const int j = t7 + (k << 3);
    const float e = SR[r][j] + ST[j][r];
    z[k] = -e;
    m = fmaxf(m, z[k]);
  }
  m = fmaxf(m, __shfl_xor(m, 1, 64));
  m = fmaxf(m, __shfl_xor(m, 2, 64));
  m = fmaxf(m, __shfl_xor(m, 4, 64));
  float ssum = 0.f;
#pragma unroll
  for (int k = 0; k < 32; ++k) { z[k] = expf(z[k] - m); ssum += z[k]; }
  ssum += __shfl_xor(ssum, 1, 64);
  ssum += __shfl_xor(ssum, 2, 64);
  ssum += __shfl_xor(ssum, 4, 64);
  const float inv = 1.f / ssum;

  u16* arow = (u16*)att + base + ((size_t)(i0 + r) << 8);
#pragma unroll
  for (int k = 0; k < 32; ++k) {
    const int j = t7 + (k << 3);
    arow[j] = (u16)f2bf(z[k] * inv);
  }
}

// ---------------------------------------------------------------------------
// Kernel 3: out = gamma * (att @ x) + x.  64(i) x 64(t) tiles, full K = 256.
// As (att, 32 KB) via global_load_lds + pre-swizzled source (R4-proven math,
// half rows).  Bs (x^T from hx, 32 KB) via R3-proven in-register repack at
// half size.  64 KB LDS -> 2 blocks/CU; grid 8192, 256 thr (4 waves 2x2,
// wave tile 32x32).  Short serial phases + co-resident block overlap.
// ---------------------------------------------------------------------------
__global__ __launch_bounds__(256, 2)
void pv_kernel(const float* __restrict__ x, const u16* __restrict__ hx,
               const __hip_bfloat16* __restrict__ att,
               const float* __restrict__ gamma, float* __restrict__ out) {
  __shared__ __align__(16) short As[64 * 256];   // rows i, k=j contig
  __shared__ __align__(16) short Bs[64 * 256];   // rows t, k=j contig

  const int tid = threadIdx.x;
  const int bx  = blockIdx.x;
  const int b   = bx >> 8;
  const int i0  = ((bx >> 6) & 3) << 6;   // 0/64/128/192
  const int t0  = (bx & 63) << 6;         // t-tile * 64

  const u16* asrc = (const u16*)att + ((size_t)b << 16) + ((size_t)i0 << 8);
  const int lane = tid & 63;
  const int w    = tid >> 6;   // 0..3

  // ---- B loads first (T14: issue early).  thread (tQ = tid&15, jg = tid>>4)
  // covers t-quad 4tQ..4tQ+3, j-range 16jg..16jg+15.
  const int tQ = tid & 15;
  const int jg = tid >> 4;     // 0..15
  const u16* hb = hx + ((size_t)b << 20) + t0 + (tQ << 2);
  uint2 v[2][8];
#pragma unroll
  for (int j8 = 0; j8 < 2; ++j8)
#pragma unroll
    for (int u = 0; u < 8; ++u)
      v[j8][u] = *(const uint2*)(hb + (size_t)((jg << 4) + (j8 << 3) + u) * TDIM);

  // ---- A stage: 32 chunks (2 rows each); wave w owns chunks c = 4s + w.
#pragma unroll
  for (int s = 0; s < 8; ++s) {
    const int c  = (s << 2) + w;
    const int r  = (c << 1) + (lane >> 5);
    const int gs = (lane & 31) ^ (r & 7);
    glds16(asrc + ((size_t)r << 8) + (gs << 3), As + (c << 9));
  }

  // ---- B repack (16-bit extract) + swizzled ds_write_b128
#pragma unroll
  for (int j8 = 0; j8 < 2; ++j8) {
#pragma unroll
    for (int tt = 0; tt < 4; ++tt) {
      unsigned p[4];
#pragma unroll
      for (int a = 0; a < 4; ++a) {
        const unsigned xa  = (tt & 2) ? v[j8][2 * a].y : v[j8][2 * a].x;
        const unsigned xb2 = (tt & 2) ? v[j8][2 * a + 1].y : v[j8][2 * a + 1].x;
        p[a] = (tt & 1) ? ((xa >> 16) | (xb2 & 0xffff0000u))
                        : ((xa & 0xffffu) | (xb2 << 16));
      }
      const int row = (tQ << 2) + tt;
      const int g   = ((jg << 1) + j8) ^ (row & 7);
      *(uint4*)(Bs + row * 256 + (g << 3)) = make_uint4(p[0], p[1], p[2], p[3]);
    }
  }

  floatx4 acc[2][2];
#pragma unroll
  for (int m = 0; m < 2; ++m)
#pragma unroll
    for (int n = 0; n < 2; ++n) acc[m][n] = {0.f, 0.f, 0.f, 0.f};

  const int wm = (w >> 1) << 5;   // 0/32
  const int wn = (w & 1) << 5;    // 0/32
  const int fr = lane & 15;
  const int q  = lane >> 4;

  __syncthreads();   // drains A glds + B ds_writes

  // ---- K-loop: fully resident, no barriers. 8 k-steps of 32 j each.
#pragma unroll
  for (int ks = 0; ks < 8; ++ks) {
    short8 Af[2], Bf[2];
#pragma unroll
    for (int m = 0; m < 2; ++m) {
      const int r = wm + 16 * m + fr;
      const int g = ((ks << 2) + q) ^ (r & 7);
      Af[m] = *(const short8*)(As + r * 256 + (g << 3));
    }
#pragma unroll
    for (int n = 0; n < 2; ++n) {
      const int r = wn + 16 * n + fr;
      const int g = ((ks << 2) + q) ^ (r & 7);
      Bf[n] = *(const short8*)(Bs + r * 256 + (g << 3));
    }
#pragma unroll
    for (int m = 0; m < 2; ++m)
#pragma unroll
      for (int n = 0; n < 2; ++n)
        acc[m][n] = __builtin_amdgcn_mfma_f32_16x16x32_bf16(Af[m], Bf[n], acc[m][n], 0, 0, 0);
  }

  const float g = gamma[0];
#pragma unroll
  for (int m = 0; m < 2; ++m)
#pragma unroll
    for (int n = 0; n < 2; ++n) {
      const int gr = i0 + wm + 16 * m + 4 * q;
      const int gc = t0 + wn + 16 * n + fr;
      size_t base = ((size_t)b << 20) + (size_t)gr * TDIM + gc;
#pragma unroll
      for (int r = 0; r < 4; ++r) {
        size_t idx = base + (size_t)r * TDIM;
        out[idx] = g * acc[m][n][r] + x[idx];
      }
    }
}

// ---------------------------------------------------------------------------
// Kernel 3-fallback: full-K pv reading x fp32 directly (bottom tier only).
// ---------------------------------------------------------------------------
__global__ __launch_bounds__(256, 1)
void pv_fused(const float* __restrict__ x, const __hip_bfloat16* __restrict__ att,
              const float* __restrict__ gamma, float* __restrict__ out) {
  __shared__ __align__(16) short As[128 * 256];
  __shared__ __align__(16) short Bs[128 * 256];

  const int tid = threadIdx.x;
  const int bx  = blockIdx.x;
  const int b   = bx >> 6;
  const int i0  = ((bx >> 5) & 1) << 7;
  const int t0  = (bx & 31) << 7;

  const float* xb = x + ((size_t)b << 20) + t0;
  const u16* attb = (const u16*)att + ((size_t)b << 16) + ((size_t)i0 << 8);

  {
    uint4 areg[16];
#pragma unroll
    for (int c = 0; c < 16; ++c) {
      const int p = (c << 8) + tid;
      const int r = p >> 5;
      const int g = (p & 31) ^ (r & 7);
      areg[c] = *(const uint4*)(attb + (r << 8) + (g << 3));
    }
#pragma unroll
    for (int c = 0; c < 16; ++c) {
      const int p = (c << 8) + tid;
      *(uint4*)((char*)As + ((size_t)p << 4)) = areg[c];
    }
  }
  {
    const int tQ = tid & 31;
    const int jg = tid >> 5;
#pragma unroll
    for (int j8 = 0; j8 < 4; ++j8) {
      floatx4 v[8];
#pragma unroll
      for (int u = 0; u < 8; ++u) {
        const int j = (jg << 5) + (j8 << 3) + u;
        v[u] = *(const floatx4*)(xb + (size_t)j * TDIM + (tQ << 2));
      }
#pragma unroll
      for (int tt = 0; tt < 4; ++tt) {
        uint4 wv = make_uint4(cvt_pk_bf16(v[0][tt], v[1][tt]),
                              cvt_pk_bf16(v[2][tt], v[3][tt]),
                              cvt_pk_bf16(v[4][tt], v[5][tt]),
                              cvt_pk_bf16(v[6][tt], v[7][tt]));
        const int row = (tQ << 2) + tt;
        const int gx  = ((jg << 2) + j8) ^ (row & 7);
        *(uint4*)((char*)Bs + (size_t)row * 512 + ((size_t)gx << 4)) = wv;
      }
    }
  }

  floatx4 acc[4][4];
#pragma unroll
  for (int m = 0; m < 4; ++m)
#pragma unroll
    for (int n = 0; n < 4; ++n) acc[m][n] = {0.f, 0.f, 0.f, 0.f};

  const int lane = tid & 63;
  const int w    = tid >> 6;
  const int wm   = (w >> 1) << 6;
  const int wn   = (w & 1) << 6;
  const int fr   = lane & 15;
  const int q    = lane >> 4;

  __syncthreads();

#pragma unroll
  for (int ks = 0; ks < 8; ++ks) {
    short8 Af[4], Bf[4];
#pragma unroll
    for (int m = 0; m < 4; ++m) {
      const int r = wm + 16 * m + fr;
      const int g = ((ks << 2) + q) ^ (r & 7);
      Af[m] = *(const short8*)((char*)As + (size_t)r * 512 + ((size_t)g << 4));
    }
#pragma unroll
    for (int n = 0; n < 4; ++n) {
      const int r = wn + 16 * n + fr;
      const int g = ((ks << 2) + q) ^ (r & 7);
      Bf[n] = *(const short8*)((char*)Bs + (size_t)r * 512 + ((size_t)g << 4));
    }
#pragma unroll
    for (int m = 0; m < 4; ++m)
#pragma unroll
      for (int n = 0; n < 4; ++n)
        acc[m][n] = __builtin_amdgcn_mfma_f32_16x16x32_bf16(Af[m], Bf[n], acc[m][n], 0, 0, 0);
  }

  const float g = gamma[0];
#pragma unroll
  for (int m = 0; m < 4; ++m)
#pragma unroll
    for (int n = 0; n < 4; ++n) {
      const int gr = i0 + wm + 16 * m + 4 * q;
      const int gc = t0 + wn + 16 * n + fr;
      size_t base = ((size_t)b << 20) + (size_t)gr * TDIM + gc;
#pragma unroll
      for (int r = 0; r < 4; ++r) {
        size_t idx = base + (size_t)r * TDIM;
        out[idx] = g * acc[m][n][r] + x[idx];
      }
    }
}

// ---------------------------------------------------------------------------
extern "C" void kernel_launch(void* const* d_in, const int* in_sizes, int n_in,
                              void* d_out, int out_size, void* d_ws, size_t ws_size,
                              hipStream_t stream) {
  (void)in_sizes; (void)n_in; (void)out_size;
  const float* x     = (const float*)d_in[0];
  const float* gamma = (const float*)d_in[1];
  float* out = (float*)d_out;

  const size_t MB = 1024 * 1024;
  const size_t EN = (size_t)BATCH * CDIM * CDIM;       // 2,097,152
  const size_t XN = (size_t)BATCH * CDIM * TDIM;       // 33,554,432
  float* S  = (float*)d_ws;                            // 8 MiB
  float* E2 = S + EN;                                  // 8 MiB
  __hip_bfloat16* att = (__hip_bfloat16*)(E2 + EN);    // 4 MiB
  u16* hx  = (u16*)((char*)d_ws + 20 * MB);            // 64 MiB
  u16* lx  = hx + XN;                                  // 64 MiB
  const size_t need = 20 * MB + 2 * XN * sizeof(u16);  // 148 MiB

  if (ws_size >= need) {
    split_kernel<<<dim3(2048), dim3(256), 0, stream>>>(x, hx, lx);
    gram_gemm<<<dim3(512), dim3(256), 0, stream>>>(hx, lx, S, E2);
    softmax_kernel<<<dim3(BATCH * 8), dim3(256), 0, stream>>>(S, E2, att);
    pv_kernel<<<dim3(8192), dim3(256), 0, stream>>>(x, hx, att, gamma, out);
  } else {
    gram_fused<<<dim3(256), dim3(512), 0, stream>>>(x, S, E2);
    softmax_kernel<<<dim3(BATCH * 8), dim3(256), 0, stream>>>(S, E2, att);
    pv_fused<<<dim3(2048), dim3(256), 0, stream>>>(x, att, gamma, out);
  }
}